// Round 1
// baseline (61.521 us; speedup 1.0000x reference)
//
#include <hip/hip_runtime.h>
#include <cmath>

namespace {

constexpr int C_    = 64;
constexpr int L_    = 32768;
constexpr int TILE  = 4096;
constexpr int HALO  = 768;            // receptive field 765, rounded to x4
constexpr int PAD   = 384;            // deepest tap reach below p=0 (3*128)
constexpr int NB    = TILE + HALO;    // 4864 floats of live buffer
constexpr int NG    = NB / 4;         // 1216 float4 groups
constexpr int NT    = L_ / TILE;      // 8 tiles per row
constexpr int BLK   = 256;
constexpr int GMAX  = (NG + BLK - 1) / BLK;   // 5 groups/thread (last pass partial)

__device__ __forceinline__ float4 ld4(const float* p) {
    return *reinterpret_cast<const float4*>(p);
}
__device__ __forceinline__ void st4(float* p, float4 v) {
    *reinterpret_cast<float4*>(p) = v;
}

__device__ __forceinline__ float gelu_exact(float v) {
    return 0.5f * v * (1.0f + erff(v * 0.7071067811865475f));
}

// One level: newlow = conv(src,h0,D); high = conv(src,h1,D); y += wi*high.
// Computes the full fixed range [0,NB); left-edge positions p < 3D*? are
// garbage but provably never read by still-valid positions (valid frontier
// advances exactly 3*D per level, total 765 <= HALO).
template<int D, bool LAST>
__device__ __forceinline__ void level_pass(const float* src, float* dst,
                                           const float* h0v, const float* h1v,
                                           float wi, float w0,
                                           float4* yacc, int tid)
{
#pragma unroll
    for (int j = 0; j < GMAX; ++j) {
        const int g = tid + j * BLK;
        if (g < NG) {
            const int p = 4 * g;
            float4 T0, T1, T2, T3;   // taps at p-3D, p-2D, p-D, p (vector of 4 outputs)
            if constexpr (D == 1) {
                float4 A  = ld4(&src[PAD + p - 4]);
                float4 Bv = ld4(&src[PAD + p]);
                T0 = make_float4(A.y, A.z, A.w, Bv.x);
                T1 = make_float4(A.z, A.w, Bv.x, Bv.y);
                T2 = make_float4(A.w, Bv.x, Bv.y, Bv.z);
                T3 = Bv;
            } else if constexpr (D == 2) {
                float4 A  = ld4(&src[PAD + p - 8]);
                float4 Bv = ld4(&src[PAD + p - 4]);
                float4 Cv = ld4(&src[PAD + p]);
                T0 = make_float4(A.z, A.w, Bv.x, Bv.y);
                T1 = Bv;
                T2 = make_float4(Bv.z, Bv.w, Cv.x, Cv.y);
                T3 = Cv;
            } else {
                T0 = ld4(&src[PAD + p - 3 * D]);
                T1 = ld4(&src[PAD + p - 2 * D]);
                T2 = ld4(&src[PAD + p - D]);
                T3 = ld4(&src[PAD + p]);
            }
            float4 hi, nl;
            hi.x = h1v[0]*T0.x + h1v[1]*T1.x + h1v[2]*T2.x + h1v[3]*T3.x;
            hi.y = h1v[0]*T0.y + h1v[1]*T1.y + h1v[2]*T2.y + h1v[3]*T3.y;
            hi.z = h1v[0]*T0.z + h1v[1]*T1.z + h1v[2]*T2.z + h1v[3]*T3.z;
            hi.w = h1v[0]*T0.w + h1v[1]*T1.w + h1v[2]*T2.w + h1v[3]*T3.w;
            nl.x = h0v[0]*T0.x + h0v[1]*T1.x + h0v[2]*T2.x + h0v[3]*T3.x;
            nl.y = h0v[0]*T0.y + h0v[1]*T1.y + h0v[2]*T2.y + h0v[3]*T3.y;
            nl.z = h0v[0]*T0.z + h0v[1]*T1.z + h0v[2]*T2.z + h0v[3]*T3.z;
            nl.w = h0v[0]*T0.w + h0v[1]*T1.w + h0v[2]*T2.w + h0v[3]*T3.w;
            yacc[j].x += wi * hi.x;
            yacc[j].y += wi * hi.y;
            yacc[j].z += wi * hi.z;
            yacc[j].w += wi * hi.w;
            if constexpr (LAST) {
                yacc[j].x += w0 * nl.x;
                yacc[j].y += w0 * nl.y;
                yacc[j].z += w0 * nl.z;
                yacc[j].w += w0 * nl.w;
            }
            st4(&dst[PAD + p], nl);
        }
    }
}

__global__ __launch_bounds__(BLK)
void cmrc_kernel(const float* __restrict__ x,
                 const float* __restrict__ h0,
                 const float* __restrict__ h1,
                 const float* __restrict__ w,
                 float* __restrict__ out)
{
    __shared__ float buf[2][PAD + NB];

    const int tid  = threadIdx.x;
    const int blk  = blockIdx.x;
    const int tile = blk % NT;
    const int bc   = blk / NT;            // b*C + c
    const int c    = bc % C_;
    const long row = (long)bc * L_;
    const int  t0  = tile * TILE - HALO;  // global pos of buffer p=0

    float h0v[4], h1v[4];
#pragma unroll
    for (int k = 0; k < 4; ++k) {
        h0v[k] = h0[c * 4 + k];
        h1v[k] = h1[c * 4 + k];
    }
    float wv[10];
#pragma unroll
    for (int i = 0; i < 10; ++i) wv[i] = w[c * 10 + i];

    float4 yacc[GMAX];

    // Stage x (with halo; zeros left of t=0) and init y = w[:,9] * x.
#pragma unroll
    for (int j = 0; j < GMAX; ++j) {
        const int g = tid + j * BLK;
        if (g < NG) {
            const int p = 4 * g;
            const int t = t0 + p;
            float4 xv = make_float4(0.f, 0.f, 0.f, 0.f);
            if (t >= 0) xv = ld4(&x[row + t]);
            st4(&buf[0][PAD + p], xv);
            yacc[j].x = wv[9] * xv.x;
            yacc[j].y = wv[9] * xv.y;
            yacc[j].z = wv[9] * xv.z;
            yacc[j].w = wv[9] * xv.w;
        }
    }
    __syncthreads();

    level_pass<1,   false>(buf[0], buf[1], h0v, h1v, wv[8], 0.f, yacc, tid); __syncthreads();
    level_pass<2,   false>(buf[1], buf[0], h0v, h1v, wv[7], 0.f, yacc, tid); __syncthreads();
    level_pass<4,   false>(buf[0], buf[1], h0v, h1v, wv[6], 0.f, yacc, tid); __syncthreads();
    level_pass<8,   false>(buf[1], buf[0], h0v, h1v, wv[5], 0.f, yacc, tid); __syncthreads();
    level_pass<16,  false>(buf[0], buf[1], h0v, h1v, wv[4], 0.f, yacc, tid); __syncthreads();
    level_pass<32,  false>(buf[1], buf[0], h0v, h1v, wv[3], 0.f, yacc, tid); __syncthreads();
    level_pass<64,  false>(buf[0], buf[1], h0v, h1v, wv[2], 0.f, yacc, tid); __syncthreads();
    level_pass<128, true >(buf[1], buf[0], h0v, h1v, wv[1], wv[0], yacc, tid);

    // Epilogue: GELU(exact erf) on owned in-tile groups, coalesced store.
#pragma unroll
    for (int j = 0; j < GMAX; ++j) {
        const int g = tid + j * BLK;
        if (g < NG) {
            const int p = 4 * g;
            if (p >= HALO) {
                float4 v = yacc[j];
                v.x = gelu_exact(v.x);
                v.y = gelu_exact(v.y);
                v.z = gelu_exact(v.z);
                v.w = gelu_exact(v.w);
                st4(&out[row + t0 + p], v);
            }
        }
    }
}

}  // namespace

extern "C" void kernel_launch(void* const* d_in, const int* in_sizes, int n_in,
                              void* d_out, int out_size, void* d_ws, size_t ws_size,
                              hipStream_t stream)
{
    const float* x  = (const float*)d_in[0];
    const float* h0 = (const float*)d_in[1];
    const float* h1 = (const float*)d_in[2];
    const float* w  = (const float*)d_in[3];
    float* out = (float*)d_out;

    const int nblocks = (out_size / L_) * NT;   // B*C*NT = 4096
    cmrc_kernel<<<nblocks, BLK, 0, stream>>>(x, h0, h1, w, out);
}

// Round 2
// 56.622 us; speedup vs baseline: 1.0865x; 1.0865x over previous
//
#include <hip/hip_runtime.h>
#include <cmath>

namespace {

constexpr int C_    = 64;
constexpr int L_    = 32768;
constexpr int TILE  = 2048;
constexpr int HALO  = 768;            // receptive field 765, rounded to x4
constexpr int HALO4 = HALO / 4;       // 192
constexpr int NB    = TILE + HALO;    // 2816 floats of live buffer
constexpr int NG    = NB / 4;         // 704 float4 groups
constexpr int NT    = L_ / TILE;      // 16 tiles per row
constexpr int BLK   = 256;
constexpr int GMAX  = (NG + BLK - 1) / BLK;   // 3 groups/thread (last partial)

__device__ __forceinline__ float4 ld4(const float* p) {
    return *reinterpret_cast<const float4*>(p);
}
__device__ __forceinline__ void st4(float* p, float4 v) {
    *reinterpret_cast<float4*>(p) = v;
}

__device__ __forceinline__ float gelu_exact(float v) {
    return 0.5f * v * (1.0f + erff(v * 0.7071067811865475f));
}

// One level (dilation D). Reads taps T0..T2 from LDS (T3 = own running low in
// registers), accumulates y += (wi*h1)·taps, computes new low with h0 and
// publishes it (except LAST, where w0*h0 is folded straight into y).
// Valid-range restriction: only groups g >= STARTG = 6D/4 are computed; the
// frontier of still-needed-valid data advances exactly 3D per level
// (total 765 <= HALO), so skipped/garbage positions are never read.
template<int D, bool LAST>
__device__ __forceinline__ void level_pass(const float* __restrict__ src,
                                           float* __restrict__ dst,
                                           const float* h0v, const float* h1v,
                                           float wi, float w0,
                                           float4* lw, float4* yacc, int tid)
{
    constexpr int STARTG = (6 * D) / 4 < 1 ? 1 : (6 * D) / 4;  // D=1 -> 1

    float a1[4], a0[4];
#pragma unroll
    for (int t = 0; t < 4; ++t) {
        a1[t] = wi * h1v[t];
        a0[t] = LAST ? w0 * h0v[t] : h0v[t];
    }

#pragma unroll
    for (int j = 0; j < GMAX; ++j) {
        const int g = tid + j * BLK;
        if (g >= STARTG && g < NG) {
            const int p = 4 * g;
            const float4 T3 = lw[j];
            float4 T0, T1, T2;
            if constexpr (D == 1) {
                float4 A = ld4(&src[p - 4]);
                T0 = make_float4(A.y, A.z, A.w, T3.x);
                T1 = make_float4(A.z, A.w, T3.x, T3.y);
                T2 = make_float4(A.w, T3.x, T3.y, T3.z);
            } else if constexpr (D == 2) {
                float4 A  = ld4(&src[p - 8]);
                float4 Bv = ld4(&src[p - 4]);
                T0 = make_float4(A.z, A.w, Bv.x, Bv.y);
                T1 = Bv;
                T2 = make_float4(Bv.z, Bv.w, T3.x, T3.y);
            } else {
                T0 = ld4(&src[p - 3 * D]);
                T1 = ld4(&src[p - 2 * D]);
                T2 = ld4(&src[p - D]);
            }
            if (g >= HALO4) {   // y only matters inside the output tile
                yacc[j].x += a1[0]*T0.x + a1[1]*T1.x + a1[2]*T2.x + a1[3]*T3.x;
                yacc[j].y += a1[0]*T0.y + a1[1]*T1.y + a1[2]*T2.y + a1[3]*T3.y;
                yacc[j].z += a1[0]*T0.z + a1[1]*T1.z + a1[2]*T2.z + a1[3]*T3.z;
                yacc[j].w += a1[0]*T0.w + a1[1]*T1.w + a1[2]*T2.w + a1[3]*T3.w;
            }
            if constexpr (!LAST) {
                float4 nl;
                nl.x = a0[0]*T0.x + a0[1]*T1.x + a0[2]*T2.x + a0[3]*T3.x;
                nl.y = a0[0]*T0.y + a0[1]*T1.y + a0[2]*T2.y + a0[3]*T3.y;
                nl.z = a0[0]*T0.z + a0[1]*T1.z + a0[2]*T2.z + a0[3]*T3.z;
                nl.w = a0[0]*T0.w + a0[1]*T1.w + a0[2]*T2.w + a0[3]*T3.w;
                lw[j] = nl;
                st4(&dst[p], nl);
            } else {
                // last level: y += w0 * newlow, newlow never published
                yacc[j].x += a0[0]*T0.x + a0[1]*T1.x + a0[2]*T2.x + a0[3]*T3.x;
                yacc[j].y += a0[0]*T0.y + a0[1]*T1.y + a0[2]*T2.y + a0[3]*T3.y;
                yacc[j].z += a0[0]*T0.z + a0[1]*T1.z + a0[2]*T2.z + a0[3]*T3.z;
                yacc[j].w += a0[0]*T0.w + a0[1]*T1.w + a0[2]*T2.w + a0[3]*T3.w;
            }
        }
    }
}

__global__ __launch_bounds__(BLK, 6)
void cmrc_kernel(const float* __restrict__ x,
                 const float* __restrict__ h0,
                 const float* __restrict__ h1,
                 const float* __restrict__ w,
                 float* __restrict__ out)
{
    __shared__ float buf[2][NB];

    const int tid  = threadIdx.x;
    const int blk  = blockIdx.x;
    const int tile = blk % NT;
    const int bc   = blk / NT;            // b*C + c
    const int c    = bc % C_;
    const long row = (long)bc * L_;
    const int  t0  = tile * TILE - HALO;  // global pos of buffer p=0

    float h0v[4], h1v[4];
#pragma unroll
    for (int k = 0; k < 4; ++k) {
        h0v[k] = h0[c * 4 + k];
        h1v[k] = h1[c * 4 + k];
    }
    float wv[10];
#pragma unroll
    for (int i = 0; i < 10; ++i) wv[i] = w[c * 10 + i];

    float4 lw[GMAX];     // running low residual for owned groups
    float4 yacc[GMAX];   // y accumulator

    // Stage x (with halo; zeros left of t=0); init lw = x, y = w[:,9]*x.
#pragma unroll
    for (int j = 0; j < GMAX; ++j) {
        yacc[j] = make_float4(0.f, 0.f, 0.f, 0.f);
        const int g = tid + j * BLK;
        if (g < NG) {
            const int p = 4 * g;
            const int t = t0 + p;
            float4 xv = make_float4(0.f, 0.f, 0.f, 0.f);
            if (t >= 0) xv = ld4(&x[row + t]);
            st4(&buf[0][p], xv);
            lw[j] = xv;
            if (g >= HALO4) {
                yacc[j].x = wv[9] * xv.x;
                yacc[j].y = wv[9] * xv.y;
                yacc[j].z = wv[9] * xv.z;
                yacc[j].w = wv[9] * xv.w;
            }
        }
    }
    __syncthreads();

    level_pass<1,   false>(buf[0], buf[1], h0v, h1v, wv[8], 0.f, lw, yacc, tid); __syncthreads();
    level_pass<2,   false>(buf[1], buf[0], h0v, h1v, wv[7], 0.f, lw, yacc, tid); __syncthreads();
    level_pass<4,   false>(buf[0], buf[1], h0v, h1v, wv[6], 0.f, lw, yacc, tid); __syncthreads();
    level_pass<8,   false>(buf[1], buf[0], h0v, h1v, wv[5], 0.f, lw, yacc, tid); __syncthreads();
    level_pass<16,  false>(buf[0], buf[1], h0v, h1v, wv[4], 0.f, lw, yacc, tid); __syncthreads();
    level_pass<32,  false>(buf[1], buf[0], h0v, h1v, wv[3], 0.f, lw, yacc, tid); __syncthreads();
    level_pass<64,  false>(buf[0], buf[1], h0v, h1v, wv[2], 0.f, lw, yacc, tid); __syncthreads();
    level_pass<128, true >(buf[1], buf[0], h0v, h1v, wv[1], wv[0], lw, yacc, tid);

    // Epilogue: GELU(exact erf) on in-tile groups, coalesced float4 store.
#pragma unroll
    for (int j = 0; j < GMAX; ++j) {
        const int g = tid + j * BLK;
        if (g >= HALO4 && g < NG) {
            const int p = 4 * g;
            float4 v = yacc[j];
            v.x = gelu_exact(v.x);
            v.y = gelu_exact(v.y);
            v.z = gelu_exact(v.z);
            v.w = gelu_exact(v.w);
            st4(&out[row + t0 + p], v);
        }
    }
}

}  // namespace

extern "C" void kernel_launch(void* const* d_in, const int* in_sizes, int n_in,
                              void* d_out, int out_size, void* d_ws, size_t ws_size,
                              hipStream_t stream)
{
    const float* x  = (const float*)d_in[0];
    const float* h0 = (const float*)d_in[1];
    const float* h1 = (const float*)d_in[2];
    const float* w  = (const float*)d_in[3];
    float* out = (float*)d_out;

    const int nblocks = (out_size / L_) * NT;   // B*C*NT = 8192
    cmrc_kernel<<<nblocks, BLK, 0, stream>>>(x, h0, h1, w, out);
}

// Round 3
// 47.545 us; speedup vs baseline: 1.2939x; 1.1909x over previous
//
#include <hip/hip_runtime.h>
#include <cmath>

namespace {

typedef _Float16 h8 __attribute__((ext_vector_type(8)));

constexpr int C_     = 64;
constexpr int L_     = 32768;
constexpr int TILE   = 4096;
constexpr int HALO   = 776;           // receptive field 765, rounded to unit-8 frontier
constexpr int NB     = TILE + HALO;   // 4872 halfs of live buffer
constexpr int NU     = NB / 8;        // 609 h8 units
constexpr int HALO_U = HALO / 8;      // 97
constexpr int NT     = L_ / TILE;     // 8 tiles per row
constexpr int BLK    = 256;
constexpr int UMAX   = (NU + BLK - 1) / BLK;   // 3 unit-slots per thread (last partial)

__device__ __forceinline__ h8 ld8(const _Float16* p) {
    return *reinterpret_cast<const h8*>(p);
}
__device__ __forceinline__ void st8(_Float16* p, h8 v) {
    *reinterpret_cast<h8*>(p) = v;
}
__device__ __forceinline__ float4 ld4f(const float* p) {
    return *reinterpret_cast<const float4*>(p);
}
__device__ __forceinline__ void st4f(float* p, float4 v) {
    *reinterpret_cast<float4*>(p) = v;
}
__device__ __forceinline__ h8 sp8(_Float16 v) {
    return (h8){v, v, v, v, v, v, v, v};
}
__device__ __forceinline__ float gelu_exact(float v) {
    return 0.5f * v * (1.0f + erff(v * 0.70710678118654752f));
}

// One level, dilation D. Each thread owns h8 units (8 consecutive elems).
// T3 = own unit (registers); T0..T2 = taps at p-3D, p-2D, p-D.
// Frontier recursion (verified): valid-start V: 0 ->8->16->32->56->104->200->392->776=HALO.
// STARTU = first unit whose reads stay >= previous V.
template<int D, int STARTU, bool LAST>
__device__ __forceinline__ void level_pass(const _Float16* __restrict__ src,
                                           _Float16* __restrict__ dst,
                                           const float* h0f, const float* h1f,
                                           float wi, float w0,
                                           h8* lw, h8* yacc, int tid)
{
    _Float16 c1[4], c0[4];
#pragma unroll
    for (int t = 0; t < 4; ++t) {
        c1[t] = (_Float16)(wi * h1f[t]);
        c0[t] = (_Float16)(LAST ? w0 * h0f[t] : h0f[t]);
    }

#pragma unroll
    for (int u = 0; u < UMAX; ++u) {
        const int un = tid + u * BLK;
        if (un >= STARTU && un < NU) {
            const int p = 8 * un;
            const h8 T3 = lw[u];
            h8 T0, T1, T2;
            if constexpr (D == 1) {
                h8 Lv = ld8(&src[p - 8]);
                T0 = __builtin_shufflevector(Lv, T3, 5, 6, 7, 8, 9, 10, 11, 12);
                T1 = __builtin_shufflevector(Lv, T3, 6, 7, 8, 9, 10, 11, 12, 13);
                T2 = __builtin_shufflevector(Lv, T3, 7, 8, 9, 10, 11, 12, 13, 14);
            } else if constexpr (D == 2) {
                h8 Lv = ld8(&src[p - 8]);
                T0 = __builtin_shufflevector(Lv, T3, 2, 3, 4, 5, 6, 7, 8, 9);
                T1 = __builtin_shufflevector(Lv, T3, 4, 5, 6, 7, 8, 9, 10, 11);
                T2 = __builtin_shufflevector(Lv, T3, 6, 7, 8, 9, 10, 11, 12, 13);
            } else if constexpr (D == 4) {
                h8 Lv  = ld8(&src[p - 8]);
                h8 LL  = ld8(&src[p - 16]);
                T0 = __builtin_shufflevector(LL, Lv, 4, 5, 6, 7, 8, 9, 10, 11);
                T1 = Lv;
                T2 = __builtin_shufflevector(Lv, T3, 4, 5, 6, 7, 8, 9, 10, 11);
            } else {
                T0 = ld8(&src[p - 3 * D]);
                T1 = ld8(&src[p - 2 * D]);
                T2 = ld8(&src[p - D]);
            }
            if (un >= HALO_U) {   // y only matters inside the output tile
                yacc[u] += sp8(c1[0]) * T0 + sp8(c1[1]) * T1
                         + sp8(c1[2]) * T2 + sp8(c1[3]) * T3;
            }
            h8 nl = sp8(c0[0]) * T0 + sp8(c0[1]) * T1
                  + sp8(c0[2]) * T2 + sp8(c0[3]) * T3;
            if constexpr (LAST) {
                yacc[u] += nl;          // c0 already folded with w0
            } else {
                lw[u] = nl;
                st8(&dst[p], nl);
            }
        }
    }
}

__global__ __launch_bounds__(BLK, 7)
void cmrc_kernel(const float* __restrict__ x,
                 const float* __restrict__ h0,
                 const float* __restrict__ h1,
                 const float* __restrict__ w,
                 float* __restrict__ out)
{
    __shared__ _Float16 buf[2][NB];

    const int tid  = threadIdx.x;
    const int blk  = blockIdx.x;
    const int tile = blk % NT;
    const int bc   = blk / NT;            // b*C + c
    const int c    = bc % C_;
    const long row = (long)bc * L_;
    const int  t0  = tile * TILE - HALO;  // global pos of buffer p=0

    float h0v[4], h1v[4];
#pragma unroll
    for (int k = 0; k < 4; ++k) {
        h0v[k] = h0[c * 4 + k];
        h1v[k] = h1[c * 4 + k];
    }
    float wv[10];
#pragma unroll
    for (int i = 0; i < 10; ++i) wv[i] = w[c * 10 + i];

    h8 lw[UMAX];     // running low residual (own units)
    h8 yacc[UMAX];   // packed y accumulator

    const _Float16 w9h = (_Float16)wv[9];

    // Stage x as fp16 (zeros left of t=0); init lw = x, y = w9*x.
#pragma unroll
    for (int u = 0; u < UMAX; ++u) {
        yacc[u] = sp8((_Float16)0.f);
        const int un = tid + u * BLK;
        if (un < NU) {
            const int p = 8 * un;
            const int t = t0 + p;
            float4 xa = make_float4(0.f, 0.f, 0.f, 0.f);
            float4 xb = make_float4(0.f, 0.f, 0.f, 0.f);
            if (t >= 0)     xa = ld4f(&x[row + t]);
            if (t + 4 >= 0) xb = ld4f(&x[row + t + 4]);
            h8 hv;
            hv[0] = (_Float16)xa.x; hv[1] = (_Float16)xa.y;
            hv[2] = (_Float16)xa.z; hv[3] = (_Float16)xa.w;
            hv[4] = (_Float16)xb.x; hv[5] = (_Float16)xb.y;
            hv[6] = (_Float16)xb.z; hv[7] = (_Float16)xb.w;
            st8(&buf[0][p], hv);
            lw[u] = hv;
            if (un >= HALO_U) yacc[u] = sp8(w9h) * hv;
        }
    }
    __syncthreads();

    level_pass<1,   1,  false>(buf[0], buf[1], h0v, h1v, wv[8], 0.f, lw, yacc, tid); __syncthreads();
    level_pass<2,   2,  false>(buf[1], buf[0], h0v, h1v, wv[7], 0.f, lw, yacc, tid); __syncthreads();
    level_pass<4,   4,  false>(buf[0], buf[1], h0v, h1v, wv[6], 0.f, lw, yacc, tid); __syncthreads();
    level_pass<8,   7,  false>(buf[1], buf[0], h0v, h1v, wv[5], 0.f, lw, yacc, tid); __syncthreads();
    level_pass<16,  13, false>(buf[0], buf[1], h0v, h1v, wv[4], 0.f, lw, yacc, tid); __syncthreads();
    level_pass<32,  25, false>(buf[1], buf[0], h0v, h1v, wv[3], 0.f, lw, yacc, tid); __syncthreads();
    level_pass<64,  49, false>(buf[0], buf[1], h0v, h1v, wv[2], 0.f, lw, yacc, tid); __syncthreads();
    level_pass<128, 97, true >(buf[1], buf[0], h0v, h1v, wv[1], wv[0], lw, yacc, tid);

    // Epilogue: unpack to fp32, exact-erf GELU, two float4 stores per unit.
#pragma unroll
    for (int u = 0; u < UMAX; ++u) {
        const int un = tid + u * BLK;
        if (un >= HALO_U && un < NU) {
            const int p = 8 * un;
            const h8 v = yacc[u];
            float4 oa, ob;
            oa.x = gelu_exact((float)v[0]); oa.y = gelu_exact((float)v[1]);
            oa.z = gelu_exact((float)v[2]); oa.w = gelu_exact((float)v[3]);
            ob.x = gelu_exact((float)v[4]); ob.y = gelu_exact((float)v[5]);
            ob.z = gelu_exact((float)v[6]); ob.w = gelu_exact((float)v[7]);
            st4f(&out[row + t0 + p], oa);
            st4f(&out[row + t0 + p + 4], ob);
        }
    }
}

}  // namespace

extern "C" void kernel_launch(void* const* d_in, const int* in_sizes, int n_in,
                              void* d_out, int out_size, void* d_ws, size_t ws_size,
                              hipStream_t stream)
{
    const float* x  = (const float*)d_in[0];
    const float* h0 = (const float*)d_in[1];
    const float* h1 = (const float*)d_in[2];
    const float* w  = (const float*)d_in[3];
    float* out = (float*)d_out;

    const int nblocks = (out_size / L_) * NT;   // B*C*NT = 4096
    cmrc_kernel<<<nblocks, BLK, 0, stream>>>(x, h0, h1, w, out);
}